// Round 5
// baseline (6378.639 us; speedup 1.0000x reference)
//
#include <hip/hip_runtime.h>
#include <cmath>

#define BROWS 16384
#define CDIM  1024
#define NIT   16

typedef __attribute__((ext_vector_type(8))) short short8;
typedef __attribute__((ext_vector_type(4))) short short4v;
typedef __attribute__((ext_vector_type(4))) float floatx4;

__device__ __forceinline__ unsigned short f2bf(float f) {
  union { float f; unsigned u; } x; x.f = f;
  unsigned r = x.u + 0x7fffu + ((x.u >> 16) & 1u);  // RNE
  return (unsigned short)(r >> 16);
}
__device__ __forceinline__ float bf2f(unsigned short h) {
  union { float f; unsigned u; } x; x.u = ((unsigned)h) << 16;
  return x.f;
}

// ---- weights fp32 -> bf16, straight + transposed, LDS-tiled (coalesced) ----
__global__ void prep_weights(const float* __restrict__ W1, const float* __restrict__ W2,
                             const float* __restrict__ W3,
                             unsigned short* __restrict__ Wb, unsigned short* __restrict__ Wt) {
  __shared__ unsigned short tile[64 * 65];
  const int bid = blockIdx.x;                 // 3 * 16 * 16
  const int m = bid >> 8, rem = bid & 255;
  const int r0 = (rem >> 4) * 64, c0 = (rem & 15) * 64;
  const float* W = (m == 0) ? W1 : ((m == 1) ? W2 : W3);
  const int t = threadIdx.x;
#pragma unroll
  for (int i = 0; i < 16; i++) {
    int idx = i * 256 + t;                    // 0..4095
    int r = idx >> 6, c = idx & 63;
    unsigned short b = f2bf(W[(size_t)(r0 + r) * CDIM + c0 + c]);
    Wb[(m << 20) + (size_t)(r0 + r) * CDIM + c0 + c] = b;
    tile[c * 65 + r] = b;
  }
  __syncthreads();
#pragma unroll
  for (int i = 0; i < 16; i++) {
    int idx = i * 256 + t;
    int cr = idx >> 6, cc = idx & 63;
    Wt[(m << 20) + (size_t)(c0 + cr) * CDIM + r0 + cc] = tile[cr * 65 + cc];
  }
}

__global__ void conv_inputs(const float* __restrict__ y, const float* __restrict__ v,
                            unsigned short* __restrict__ ybf, unsigned short* __restrict__ wbf,
                            float* __restrict__ inner) {
  int i = (blockIdx.x * 256 + threadIdx.x) * 4;   // vectorized x4
  floatx4 yv = *(const floatx4*)(y + i);
  floatx4 vv = *(const floatx4*)(v + i);
  short4v a, b;
#pragma unroll
  for (int r = 0; r < 4; r++) { a[r] = (short)f2bf(yv[r]); b[r] = (short)f2bf(vv[r]); }
  *(short4v*)(ybf + i) = a;
  *(short4v*)(wbf + i) = b;
  if (i < NIT * BROWS) *(floatx4*)(inner + i) = floatx4{0.f, 0.f, 0.f, 0.f};
}

// v fp32 -> bf16 into the (free after GEMM1) ybf buffer
__global__ void conv_v(const float* __restrict__ v, unsigned short* __restrict__ vb) {
  int i = (blockIdx.x * 256 + threadIdx.x) * 8;
  floatx4 a = *(const floatx4*)(v + i);
  floatx4 b = *(const floatx4*)(v + i + 4);
  short8 o;
#pragma unroll
  for (int r = 0; r < 4; r++) { o[r] = (short)f2bf(a[r]); o[r + 4] = (short)f2bf(b[r]); }
  *(short8*)(vb + i) = o;
}

// ---- Register-direct GEMM: C[m,n] = sum_k A[m,k]*B[n,k] ----
// NO LDS staging, NO barriers. Block = 4 independent waves stacked in m;
// each wave computes 64m x 64n, loading MFMA fragments STRAIGHT from global:
// lane reads 16 B at row(ln), col quad*16+k -- a wave touches 16 rows x 64 B
// fully-covered lines (same segment count as a coalesced 1 KB load). B rows
// are identical across the 4 waves (L1 hits); A re-reads across n-blocks hit
// the per-XCD L2 (4 MB m-slab via swizzle). The compiler pipelines plain
// register loads across the unrolled K-loop; waves never couple on barriers.
// MODE 0: FWD   outB=bf16(elu(acc+bias)), outD=bf16(elu')
// MODE 1: FWD3  outZ = acc + bias + yin (fp32)
// MODE 2: BWD   outB = bf16(acc * Dm)
// MODE 3: BWD3  outB = bf16(acc); inner[row] += sum_n acc*vin
template <int MODE>
__global__ __launch_bounds__(256)
void gemm_r(const unsigned short* __restrict__ A,
            const unsigned short* __restrict__ Bm,
            const float* __restrict__ bias,
            const float* __restrict__ yin,
            const unsigned short* __restrict__ Dm,
            const unsigned short* __restrict__ vin,
            unsigned short* __restrict__ outB,
            unsigned short* __restrict__ outD,
            float* __restrict__ outZ,
            float* __restrict__ inner) {
  constexpr int K = CDIM, N = CDIM;
  __shared__ unsigned short Ct[4][64 * 68];     // per-wave epilogue transpose tile

  const int t = threadIdx.x;
  const int w = t >> 6, lane = t & 63;
  const int quad = lane >> 4, ln = lane & 15;

  // XCD swizzle: xcd = lb&7 owns a contiguous 2048-row m-slab (4 MB = its L2).
  const int lb = blockIdx.x;                    // 0..1023
  const int i = lb >> 3;                        // 0..127
  const int m0 = ((lb & 7) * 8 + (i >> 4)) * 256;
  const int n0 = (i & 15) * 64;
  const int mw = m0 + w * 64;                   // this wave's 64-row slab

  const unsigned short* pA = A + (size_t)(mw + ln) * K + quad * 8;
  const unsigned short* pB = Bm + (size_t)(n0 + ln) * K + quad * 8;

  floatx4 acc[4][4];
#pragma unroll
  for (int a = 0; a < 4; a++)
#pragma unroll
    for (int b = 0; b < 4; b++) acc[a][b] = {0.f, 0.f, 0.f, 0.f};

  short8 aC[4], bC[4];
#pragma unroll
  for (int mi = 0; mi < 4; mi++) aC[mi] = *(const short8*)(pA + (size_t)mi * 16 * K);
#pragma unroll
  for (int ni = 0; ni < 4; ni++) bC[ni] = *(const short8*)(pB + (size_t)ni * 16 * K);

#pragma unroll 4
  for (int k = 0; k < 31; k++) {
    const int ko = (k + 1) * 32;
    short8 aN[4], bN[4];
#pragma unroll
    for (int mi = 0; mi < 4; mi++) aN[mi] = *(const short8*)(pA + (size_t)mi * 16 * K + ko);
#pragma unroll
    for (int ni = 0; ni < 4; ni++) bN[ni] = *(const short8*)(pB + (size_t)ni * 16 * K + ko);
#pragma unroll
    for (int mi = 0; mi < 4; mi++)
#pragma unroll
      for (int ni = 0; ni < 4; ni++)
        acc[mi][ni] = __builtin_amdgcn_mfma_f32_16x16x32_bf16(aC[mi], bC[ni], acc[mi][ni], 0, 0, 0);
#pragma unroll
    for (int mi = 0; mi < 4; mi++) aC[mi] = aN[mi];
#pragma unroll
    for (int ni = 0; ni < 4; ni++) bC[ni] = bN[ni];
  }
#pragma unroll
  for (int mi = 0; mi < 4; mi++)
#pragma unroll
    for (int ni = 0; ni < 4; ni++)
      acc[mi][ni] = __builtin_amdgcn_mfma_f32_16x16x32_bf16(aC[mi], bC[ni], acc[mi][ni], 0, 0, 0);

  // ---- per-wave epilogue: transpose via this wave's private LDS tile, then
  // coalesced global I/O (no cross-wave sync needed) ----
  unsigned short* ct = Ct[w];
  const int lr0 = quad * 4;

  if (MODE == 0) {
    float bv[4];
#pragma unroll
    for (int ni = 0; ni < 4; ni++) bv[ni] = bias[n0 + ni * 16 + ln];
#pragma unroll
    for (int mi = 0; mi < 4; mi++)
#pragma unroll
      for (int ni = 0; ni < 4; ni++)
#pragma unroll
        for (int r = 0; r < 4; r++) {
          float p = acc[mi][ni][r] + bv[ni];
          float e = (p > 0.f) ? p : expm1f(p);
          ct[(mi * 16 + lr0 + r) * 68 + ni * 16 + ln] = f2bf(e);
        }
  } else {
#pragma unroll
    for (int mi = 0; mi < 4; mi++)
#pragma unroll
      for (int ni = 0; ni < 4; ni++)
#pragma unroll
        for (int r = 0; r < 4; r++)
          ct[(mi * 16 + lr0 + r) * 68 + ni * 16 + ln] = f2bf(acc[mi][ni][r]);
  }

  const int orow = lane >> 3;                   // 0..7
  const int ocol = (lane & 7) * 8;              // 0..56 (elems)
#pragma unroll
  for (int it = 0; it < 8; it++) {
    const int lr = it * 8 + orow;               // 0..63
    short4v v0 = *(const short4v*)&ct[lr * 68 + ocol];
    short4v v1 = *(const short4v*)&ct[lr * 68 + ocol + 4];
    short8 val;
#pragma unroll
    for (int j = 0; j < 4; j++) { val[j] = v0[j]; val[j + 4] = v1[j]; }
    const size_t o = (size_t)(mw + lr) * N + (n0 + ocol);
    if (MODE == 0) {
      *(short8*)&outB[o] = val;
      short8 dd;
#pragma unroll
      for (int j = 0; j < 8; j++) {
        float e = bf2f((unsigned short)val[j]);
        dd[j] = (short)f2bf(e > 0.f ? 1.f : e + 1.f);   // elu' from staged elu
      }
      *(short8*)&outD[o] = dd;
    } else if (MODE == 1) {
      const floatx4 y0 = *(const floatx4*)&yin[o];
      const floatx4 y1 = *(const floatx4*)&yin[o + 4];
      const floatx4 b0 = *(const floatx4*)&bias[n0 + ocol];
      const floatx4 b1 = *(const floatx4*)&bias[n0 + ocol + 4];
      floatx4 z0, z1;
#pragma unroll
      for (int j = 0; j < 4; j++) {
        z0[j] = bf2f((unsigned short)val[j]) + b0[j] + y0[j];
        z1[j] = bf2f((unsigned short)val[j + 4]) + b1[j] + y1[j];
      }
      *(floatx4*)&outZ[o] = z0;
      *(floatx4*)&outZ[o + 4] = z1;
    } else if (MODE == 2) {
      short8 d = *(const short8*)&Dm[o];
      short8 ov;
#pragma unroll
      for (int j = 0; j < 8; j++)
        ov[j] = (short)f2bf(bf2f((unsigned short)val[j]) * bf2f((unsigned short)d[j]));
      *(short8*)&outB[o] = ov;
    } else {  // MODE 3
      *(short8*)&outB[o] = val;
      short8 vv = *(const short8*)&vin[o];
      float ps = 0.f;
#pragma unroll
      for (int j = 0; j < 8; j++)
        ps += bf2f((unsigned short)val[j]) * bf2f((unsigned short)vv[j]);
      ps += __shfl_xor(ps, 1);
      ps += __shfl_xor(ps, 2);
      ps += __shfl_xor(ps, 4);
      if ((lane & 7) == 0) atomicAdd(&inner[mw + lr], ps);
    }
  }
}

__global__ void combine_ldj(const float* __restrict__ ldj_in, const float* __restrict__ inner,
                            float* __restrict__ out) {
  int b = blockIdx.x * 256 + threadIdx.x;
  if (b < BROWS) {
    float a = ldj_in[b];
#pragma unroll
    for (int k = 1; k <= NIT; k++) {
      float s = (k & 1) ? 1.f : -1.f;       // odd k: +, even k: -
      a += s * inner[(k - 1) * BROWS + b] / (float)k;
    }
    out[b] = a;
  }
}

extern "C" void kernel_launch(void* const* d_in, const int* in_sizes, int n_in,
                              void* d_out, int out_size, void* d_ws, size_t ws_size,
                              hipStream_t stream) {
  const float* y   = (const float*)d_in[0];
  const float* ldj = (const float*)d_in[1];
  const float* v   = (const float*)d_in[2];
  const float* W1  = (const float*)d_in[3];
  const float* b1  = (const float*)d_in[4];
  const float* W2  = (const float*)d_in[5];
  const float* b2  = (const float*)d_in[6];
  const float* W3  = (const float*)d_in[7];
  const float* b3  = (const float*)d_in[8];

  float* z_out   = (float*)d_out;                         // B*C fp32
  float* ldj_out = z_out + (size_t)BROWS * CDIM;          // B fp32

  const size_t MC = (size_t)BROWS * CDIM;                 // 16M elems
  const size_t WW = (size_t)3 * CDIM * CDIM;              // 3M elems
  unsigned short* Wb    = (unsigned short*)d_ws;          // 6 MB
  unsigned short* Wt    = Wb + WW;                        // 6 MB
  float*          inner = (float*)(Wt + WW);              // 1 MB
  unsigned short* ybf   = (unsigned short*)(inner + NIT * BROWS);
  unsigned short* ua    = ybf + MC;                       // 32 MB each
  unsigned short* ub    = ua + MC;
  unsigned short* wv    = ub + MC;
  unsigned short* d1    = wv + MC;
  unsigned short* d2    = d1 + MC;

  prep_weights<<<768, 256, 0, stream>>>(W1, W2, W3, Wb, Wt);
  conv_inputs<<<(BROWS * CDIM) / (256 * 4), 256, 0, stream>>>(y, v, ybf, wv, inner);

  dim3 grid(1024);  // 64 m-blocks (256 rows) x 16 n-blocks (64 cols), XCD-swizzled

  // forward: h1=elu(y@W1^T+b1), h2=elu(h1@W2^T+b2), z=y+h2@W3^T+b3
  gemm_r<0><<<grid, 256, 0, stream>>>(ybf, Wb,             b1, nullptr, nullptr, nullptr, ua, d1, nullptr, nullptr);
  // ybf free after GEMM1 -> bf16(v)
  conv_v<<<(BROWS * CDIM) / (256 * 8), 256, 0, stream>>>(v, ybf);
  gemm_r<0><<<grid, 256, 0, stream>>>(ua,  Wb + (1 << 20), b2, nullptr, nullptr, nullptr, ub, d2, nullptr, nullptr);
  gemm_r<1><<<grid, 256, 0, stream>>>(ub,  Wb + (2 << 20), b3, y,       nullptr, nullptr, nullptr, nullptr, z_out, nullptr);

  // power series: w <- ((w@W3)*d2 @ W2)*d1 @ W1 ; inner_k = <w, v>
  for (int k = 1; k <= NIT; k++) {
    gemm_r<2><<<grid, 256, 0, stream>>>(wv, Wt + (2 << 20), nullptr, nullptr, d2, nullptr, ua, nullptr, nullptr, nullptr);
    gemm_r<2><<<grid, 256, 0, stream>>>(ua, Wt + (1 << 20), nullptr, nullptr, d1, nullptr, ub, nullptr, nullptr, nullptr);
    gemm_r<3><<<grid, 256, 0, stream>>>(ub, Wt,             nullptr, nullptr, nullptr, ybf, wv, nullptr, nullptr, inner + (size_t)(k - 1) * BROWS);
  }

  combine_ldj<<<(BROWS + 255) / 256, 256, 0, stream>>>(ldj, inner, ldj_out);
}